// Round 2
// baseline (50.291 us; speedup 1.0000x reference)
//
#include <hip/hip_runtime.h>

// Pairlist: 1024 molecules x 100 atoms, all ordered pairs i != j.
// 9900 pairs/molecule, NP = 10,137,600 pairs total.
//
// Output layout (float32, flat):
//   [0    , NP)   : pair index i (as float)
//   [NP   , 2NP)  : pair index j
//   [2NP  , 3NP)  : d_ij
//   [3NP  , 6NP)  : r_ij (NP,3) row-major
//
// 4 pairs per thread -> all stores are 16B-aligned float4:
//   i,j,d: out[4t..4t+3]           (byte 16t, aligned)
//   r_ij : floats [12t, 12t+12)    (byte 48t, 16B aligned)
// PPM = 9900 is divisible by 4, so 4 consecutive pairs share one molecule.

#define N_MOL 1024
#define APM   100
#define PPM   (APM * (APM-1))     // 9900
#define NP    (N_MOL * PPM)       // 10,137,600
#define NTHREADS (NP / 4)         // 2,534,400

__global__ __launch_bounds__(256) void pairlist_kernel(
    const float* __restrict__ pos,   // (102400, 3)
    float* __restrict__ out)
{
    unsigned t = blockIdx.x * blockDim.x + threadIdx.x;
    if (t >= NTHREADS) return;

    unsigned p0 = t * 4u;
    unsigned m  = p0 / (unsigned)PPM;
    unsigned r0 = p0 - m * (unsigned)PPM;
    unsigned base = m * (unsigned)APM;
    const float* mp = pos + (size_t)base * 3u;   // molecule's positions

    float4 fi, fj, fd;
    float rxyz[12];

    #pragma unroll
    for (int q = 0; q < 4; ++q) {
        unsigned r  = r0 + (unsigned)q;
        unsigned il = r / 99u;
        unsigned k  = r - il * 99u;
        unsigned jl = k + (k >= il ? 1u : 0u);

        float xi = mp[3u*il+0u], yi = mp[3u*il+1u], zi = mp[3u*il+2u];
        float xj = mp[3u*jl+0u], yj = mp[3u*jl+1u], zj = mp[3u*jl+2u];
        float rx = xj - xi, ry = yj - yi, rz = zj - zi;

        ((float*)&fi)[q] = (float)(base + il);
        ((float*)&fj)[q] = (float)(base + jl);
        ((float*)&fd)[q] = sqrtf(rx*rx + ry*ry + rz*rz);
        rxyz[3*q+0] = rx; rxyz[3*q+1] = ry; rxyz[3*q+2] = rz;
    }

    float4* oi = (float4*)(out) + t;
    float4* oj = (float4*)(out + (size_t)NP) + t;
    float4* od = (float4*)(out + (size_t)2*NP) + t;
    *oi = fi; *oj = fj; *od = fd;

    float4* orr = (float4*)(out + (size_t)3*NP) + (size_t)3*t;
    orr[0] = make_float4(rxyz[0], rxyz[1], rxyz[2],  rxyz[3]);
    orr[1] = make_float4(rxyz[4], rxyz[5], rxyz[6],  rxyz[7]);
    orr[2] = make_float4(rxyz[8], rxyz[9], rxyz[10], rxyz[11]);
}

extern "C" void kernel_launch(void* const* d_in, const int* in_sizes, int n_in,
                              void* d_out, int out_size, void* d_ws, size_t ws_size,
                              hipStream_t stream) {
    const float* pos = (const float*)d_in[0];
    float* out = (float*)d_out;
    int nblocks = (NTHREADS + 255) / 256;
    pairlist_kernel<<<nblocks, 256, 0, stream>>>(pos, out);
}

// Round 3
// 45.357 us; speedup vs baseline: 1.1088x; 1.1088x over previous
//
#include <hip/hip_runtime.h>

// Pairlist: 1024 molecules x 100 atoms, all ordered pairs i != j.
// 9900 pairs/molecule, NP = 10,137,600 pairs total.
//
// Output layout (float32, flat):
//   [0    , NP)   : pair index i (as float)
//   [NP   , 2NP)  : pair index j
//   [2NP  , 3NP)  : d_ij
//   [3NP  , 6NP)  : r_ij (NP,3) row-major
//
// 256 threads/block, 4 pairs/thread -> 1024 pairs/block.
//   i,j,d : direct float4 stores, lane-contiguous (16B/lane)  [coalesced]
//   r_ij  : staged through LDS (12 KB), then written as 768 contiguous
//           float4s per block (3/thread, 16B/lane)            [coalesced]
// 9900 % 4 == 0 so a thread's 4 pairs never cross a molecule boundary.

#define N_MOL 1024
#define APM   100
#define PPM   (APM * (APM-1))     // 9900
#define NP    (N_MOL * PPM)       // 10,137,600
#define NTHREADS (NP / 4)         // 2,534,400
#define NBLOCKS  (NTHREADS / 256) // 9900

__global__ __launch_bounds__(256) void pairlist_kernel(
    const float* __restrict__ pos,   // (102400, 3)
    float* __restrict__ out)
{
    __shared__ float lds[3072];      // 1024 pairs * 3 comps = 12 KB

    unsigned lt = threadIdx.x;
    unsigned t  = blockIdx.x * 256u + lt;

    unsigned p0 = t * 4u;
    unsigned m  = p0 / (unsigned)PPM;
    unsigned r0 = p0 - m * (unsigned)PPM;
    unsigned base = m * (unsigned)APM;
    const float* mp = pos + (size_t)base * 3u;   // this molecule's positions

    float4 fi, fj, fd;
    float rxyz[12];

    #pragma unroll
    for (int q = 0; q < 4; ++q) {
        unsigned r  = r0 + (unsigned)q;
        unsigned il = r / 99u;
        unsigned k  = r - il * 99u;
        unsigned jl = k + (k >= il ? 1u : 0u);

        float xi = mp[3u*il+0u], yi = mp[3u*il+1u], zi = mp[3u*il+2u];
        float xj = mp[3u*jl+0u], yj = mp[3u*jl+1u], zj = mp[3u*jl+2u];
        float rx = xj - xi, ry = yj - yi, rz = zj - zi;

        ((float*)&fi)[q] = (float)(base + il);
        ((float*)&fj)[q] = (float)(base + jl);
        ((float*)&fd)[q] = sqrtf(rx*rx + ry*ry + rz*rz);
        rxyz[3*q+0] = rx; rxyz[3*q+1] = ry; rxyz[3*q+2] = rz;
    }

    // i, j, d: lane-contiguous float4 stores
    ((float4*)(out))[t]                 = fi;
    ((float4*)(out + (size_t)NP))[t]    = fj;
    ((float4*)(out + (size_t)2*NP))[t]  = fd;

    // r_ij: stage to LDS, then write block's 3 KB region fully coalesced
    float4* lds4 = (float4*)lds;
    #pragma unroll
    for (int s = 0; s < 3; ++s)
        lds4[3u*lt + s] = make_float4(rxyz[4*s+0], rxyz[4*s+1],
                                      rxyz[4*s+2], rxyz[4*s+3]);
    __syncthreads();

    float4* orr = (float4*)(out + (size_t)3*NP) + (size_t)768 * blockIdx.x;
    #pragma unroll
    for (int s = 0; s < 3; ++s)
        orr[lt + 256u*s] = lds4[lt + 256u*s];
}

extern "C" void kernel_launch(void* const* d_in, const int* in_sizes, int n_in,
                              void* d_out, int out_size, void* d_ws, size_t ws_size,
                              hipStream_t stream) {
    const float* pos = (const float*)d_in[0];
    float* out = (float*)d_out;
    pairlist_kernel<<<NBLOCKS, 256, 0, stream>>>(pos, out);
}